// Round 3
// baseline (702.851 us; speedup 1.0000x reference)
//
#include <hip/hip_runtime.h>
#include <hip/hip_bf16.h>
#include <cstdint>

// LSTMCell B=4096, IN=H=2048. gates[B,8192] = X@Wx^T + Hm@Wh^T + b, then
// pointwise combine. Correctness-bisect round: (1) no global_load_lds —
// plain ds_write staging; (2) runtime dtype probe (bf16 vs fp32 inputs)
// with uniform in-kernel branch; MFMA core is bf16 either way.

#define B_DIM 4096
#define K_DIM 2048            // IN == H
#define NG    8192            // 4*H
#define BHT   (B_DIM * K_DIM) // B*H elements per output tensor

using bf16x8_t  = __attribute__((ext_vector_type(8))) __bf16;
using floatx4_t = __attribute__((ext_vector_type(4))) float;
using ushort8_t = __attribute__((ext_vector_type(8))) unsigned short;

__device__ __forceinline__ float bf_bits2f(unsigned short u) {
    return __builtin_bit_cast(float, ((unsigned int)u) << 16);
}
__device__ __forceinline__ unsigned short f2bf_bits(float f) {
    return __builtin_bit_cast(unsigned short, __float2bfloat16(f));
}
__device__ __forceinline__ float sigmoid_f(float x) {
    return 1.0f / (1.0f + __expf(-x));
}
__device__ __forceinline__ float tanh_f(float x) {
    float ax = fabsf(x);
    float e  = __expf(-2.0f * ax);
    float t  = (1.0f - e) / (1.0f + e);
    return copysignf(t, x);
}

// ---------------------------------------------------------------------------
// Dtype probe: X ~ N(0,1). If buffer is bf16, both 16-bit halves of each
// 32-bit word are sane bf16 (exponent near 127). If fp32, low halves are
// mantissa bits (~20% sane). flag: 0 = bf16, 1 = fp32.
// ---------------------------------------------------------------------------
__global__ void dtype_probe_kernel(const unsigned int* __restrict__ X,
                                   int* __restrict__ flag) {
    const int lane = threadIdx.x;             // 64 threads, 1 block
    const unsigned int w = X[lane];
    const unsigned short hi = (unsigned short)(w >> 16);
    const unsigned short lo = (unsigned short)(w & 0xFFFFu);
    auto sane = [](unsigned short h) -> int {
        const int e = (h >> 7) & 0xFF;
        return (e >= 90 && e <= 140) || ((h & 0x7FFF) == 0);
    };
    const unsigned long long bh = __ballot(sane(hi));
    const unsigned long long bl = __ballot(sane(lo));
    if (lane == 0) {
        const int cnt = __popcll(bh) + __popcll(bl);  // bf16 ≈ 128, fp32 ≈ 77
        *flag = (cnt >= 112) ? 0 : 1;
    }
}

// ---------------------------------------------------------------------------
// Kernel 1: gates GEMM, one M-chunk. 128x128 tile/block, 256 thr = 4 waves
// (2x2), each wave 64x64 via 4x4 mfma_f32_16x16x32_bf16, BK=32.
// Staging: global -> VGPR (ushort8 or float8+cvt) -> ds_write_b128.
// LDS: As[128][32] bf16 @0, Bs[128][32] bf16 @8192, K-major, unpadded.
// ---------------------------------------------------------------------------
__global__ __launch_bounds__(256) void gates_gemm_kernel(
    const void* __restrict__ X,   // [4096,2048]
    const void* __restrict__ Hm,  // [4096,2048]
    const void* __restrict__ Wx0, const void* __restrict__ Wx1,
    const void* __restrict__ Wx2, const void* __restrict__ Wx3,
    const void* __restrict__ Wh0, const void* __restrict__ Wh1,
    const void* __restrict__ Wh2, const void* __restrict__ Wh3,
    const void* __restrict__ bi0, const void* __restrict__ bi1,
    const void* __restrict__ bi2, const void* __restrict__ bi3,
    const int* __restrict__ flagp, int m0,
    __hip_bfloat16* __restrict__ gates)     // [rows,8192] chunk-local
{
    __shared__ __align__(16) char lds[16384];

    const int isF32 = *flagp;                 // uniform
    const int esz   = isF32 ? 4 : 2;

    const int tid     = threadIdx.x;
    const int bm      = blockIdx.y;           // M tile within chunk
    const int bn      = blockIdx.x;           // 0..63, gate-major
    const int gate    = bn >> 4;
    const int nInGate = (bn & 15) << 7;

    const void* Wx = (gate == 0) ? Wx0 : (gate == 1) ? Wx1 : (gate == 2) ? Wx2 : Wx3;
    const void* Wh = (gate == 0) ? Wh0 : (gate == 1) ? Wh1 : (gate == 2) ? Wh2 : Wh3;
    const void* bs = (gate == 0) ? bi0 : (gate == 1) ? bi1 : (gate == 2) ? bi2 : bi3;

    // staging geometry: thread t handles row (t>>2), 8 elements at sub=(t&3)*8
    // within each 32-element K slab; LDS dest byte = t*16 (+4096 for rows 64+).
    const int ldRow = tid >> 2;
    const int sub   = tid & 3;
    const size_t rowStride = (size_t)K_DIM * esz;
    const size_t rowHalf   = 64 * rowStride;
    const char* aG  = (const char*)X  + (size_t)(m0 + bm * 128 + ldRow) * rowStride + (size_t)sub * 8 * esz;
    const char* hG  = (const char*)Hm + (size_t)(m0 + bm * 128 + ldRow) * rowStride + (size_t)sub * 8 * esz;
    const char* wxG = (const char*)Wx + (size_t)(nInGate + ldRow) * rowStride + (size_t)sub * 8 * esz;
    const char* whG = (const char*)Wh + (size_t)(nInGate + ldRow) * rowStride + (size_t)sub * 8 * esz;

    char* const dA0 = lds + tid * 16;          // As rows 0..63
    char* const dA1 = lds + 4096 + tid * 16;   // As rows 64..127
    char* const dB0 = lds + 8192 + tid * 16;   // Bs rows 0..63
    char* const dB1 = lds + 12288 + tid * 16;  // Bs rows 64..127
    const char* const AsB = lds;
    const char* const BsB = lds + 8192;

    const int lane = tid & 63;
    const int wave = tid >> 6;
    const int wm   = (wave & 1) << 6;
    const int wn   = (wave >> 1) << 6;
    const int lr   = lane & 15;   // A row / B col within 16
    const int quad = lane >> 4;   // k-group: k = quad*8 .. +8

    int aOff[4], bOff[4];
#pragma unroll
    for (int i = 0; i < 4; ++i) {
        aOff[i] = ((wm + i * 16 + lr) * 32 + quad * 8) * 2;
        bOff[i] = ((wn + i * 16 + lr) * 32 + quad * 8) * 2;
    }

    floatx4_t acc[4][4];
#pragma unroll
    for (int mi = 0; mi < 4; ++mi)
#pragma unroll
        for (int ni = 0; ni < 4; ++ni)
            acc[mi][ni] = (floatx4_t){0.f, 0.f, 0.f, 0.f};

#pragma unroll 1
    for (int seg = 0; seg < 2; ++seg) {
        const char* ag = seg ? hG : aG;
        const char* bg = seg ? whG : wxG;
#pragma unroll 1
        for (int ke = 0; ke < K_DIM; ke += 32) {
            const size_t kb = (size_t)ke * esz;
            ushort8_t va0, va1, vb0, vb1;
            if (!isF32) {
                va0 = *reinterpret_cast<const ushort8_t*>(ag + kb);
                va1 = *reinterpret_cast<const ushort8_t*>(ag + rowHalf + kb);
                vb0 = *reinterpret_cast<const ushort8_t*>(bg + kb);
                vb1 = *reinterpret_cast<const ushort8_t*>(bg + rowHalf + kb);
            } else {
                const char* p;
                float4 f0, f1;
                p = ag + kb;           f0 = *reinterpret_cast<const float4*>(p);
                f1 = *reinterpret_cast<const float4*>(p + 16);
                va0 = (ushort8_t){f2bf_bits(f0.x), f2bf_bits(f0.y), f2bf_bits(f0.z), f2bf_bits(f0.w),
                                  f2bf_bits(f1.x), f2bf_bits(f1.y), f2bf_bits(f1.z), f2bf_bits(f1.w)};
                p = ag + rowHalf + kb; f0 = *reinterpret_cast<const float4*>(p);
                f1 = *reinterpret_cast<const float4*>(p + 16);
                va1 = (ushort8_t){f2bf_bits(f0.x), f2bf_bits(f0.y), f2bf_bits(f0.z), f2bf_bits(f0.w),
                                  f2bf_bits(f1.x), f2bf_bits(f1.y), f2bf_bits(f1.z), f2bf_bits(f1.w)};
                p = bg + kb;           f0 = *reinterpret_cast<const float4*>(p);
                f1 = *reinterpret_cast<const float4*>(p + 16);
                vb0 = (ushort8_t){f2bf_bits(f0.x), f2bf_bits(f0.y), f2bf_bits(f0.z), f2bf_bits(f0.w),
                                  f2bf_bits(f1.x), f2bf_bits(f1.y), f2bf_bits(f1.z), f2bf_bits(f1.w)};
                p = bg + rowHalf + kb; f0 = *reinterpret_cast<const float4*>(p);
                f1 = *reinterpret_cast<const float4*>(p + 16);
                vb1 = (ushort8_t){f2bf_bits(f0.x), f2bf_bits(f0.y), f2bf_bits(f0.z), f2bf_bits(f0.w),
                                  f2bf_bits(f1.x), f2bf_bits(f1.y), f2bf_bits(f1.z), f2bf_bits(f1.w)};
            }
            __syncthreads();   // prev iter's ds_reads done before overwrite
            *reinterpret_cast<ushort8_t*>(dA0) = va0;
            *reinterpret_cast<ushort8_t*>(dA1) = va1;
            *reinterpret_cast<ushort8_t*>(dB0) = vb0;
            *reinterpret_cast<ushort8_t*>(dB1) = vb1;
            __syncthreads();   // writes visible

            bf16x8_t af[4], bw[4];
#pragma unroll
            for (int i = 0; i < 4; ++i) af[i] = *reinterpret_cast<const bf16x8_t*>(AsB + aOff[i]);
#pragma unroll
            for (int i = 0; i < 4; ++i) bw[i] = *reinterpret_cast<const bf16x8_t*>(BsB + bOff[i]);
#pragma unroll
            for (int mi = 0; mi < 4; ++mi)
#pragma unroll
                for (int ni = 0; ni < 4; ++ni)
                    acc[mi][ni] = __builtin_amdgcn_mfma_f32_16x16x32_bf16(
                        af[mi], bw[ni], acc[mi][ni], 0, 0, 0);
        }
    }

    // Epilogue: C/D layout col=lane&15, row=quad*4+reg (m89-verified). +bias.
    float bv[4];
#pragma unroll
    for (int ni = 0; ni < 4; ++ni) {
        const int col = nInGate + wn + ni * 16 + lr;
        bv[ni] = isF32 ? ((const float*)bs)[col]
                       : __bfloat162float(((const __hip_bfloat16*)bs)[col]);
    }

#pragma unroll
    for (int mi = 0; mi < 4; ++mi) {
        const int rowBase = bm * 128 + wm + mi * 16 + quad * 4;
#pragma unroll
        for (int ni = 0; ni < 4; ++ni) {
            const size_t colBase = (size_t)gate * 2048 + nInGate + wn + ni * 16 + lr;
#pragma unroll
            for (int r = 0; r < 4; ++r)
                gates[(size_t)(rowBase + r) * NG + colBase] =
                    __float2bfloat16(acc[mi][ni][r] + bv[ni]);
        }
    }
}

// ---------------------------------------------------------------------------
// Kernel 2: pointwise LSTM combine, one M-chunk. 4 elements/thread.
// gates always bf16 (ws); Cin / outputs dtype per flag.
// ---------------------------------------------------------------------------
__global__ __launch_bounds__(256) void lstm_pointwise_kernel(
    const unsigned short* __restrict__ gates,
    const void* __restrict__ Cin,
    void* __restrict__ out,
    const int* __restrict__ flagp, int m0)
{
    const int isF32 = *flagp;
    const int lidx = (blockIdx.x * 256 + threadIdx.x) * 4;   // chunk-local B*H idx
    const int b = lidx >> 11;
    const int j = lidx & 2047;
    const unsigned short* g = gates + (size_t)b * NG + j;
    const size_t gidx = (size_t)m0 * 2048 + (size_t)lidx;    // global B*H idx

    const ushort4 ui = *reinterpret_cast<const ushort4*>(g);
    const ushort4 uo = *reinterpret_cast<const ushort4*>(g + 2048);
    const ushort4 uf = *reinterpret_cast<const ushort4*>(g + 4096);
    const ushort4 uc = *reinterpret_cast<const ushort4*>(g + 6144);
    const float gi[4] = {bf_bits2f(ui.x), bf_bits2f(ui.y), bf_bits2f(ui.z), bf_bits2f(ui.w)};
    const float go[4] = {bf_bits2f(uo.x), bf_bits2f(uo.y), bf_bits2f(uo.z), bf_bits2f(uo.w)};
    const float gf[4] = {bf_bits2f(uf.x), bf_bits2f(uf.y), bf_bits2f(uf.z), bf_bits2f(uf.w)};
    const float gc[4] = {bf_bits2f(uc.x), bf_bits2f(uc.y), bf_bits2f(uc.z), bf_bits2f(uc.w)};

    float cv[4];
    if (isF32) {
        const float4 c4 = *reinterpret_cast<const float4*>((const float*)Cin + gidx);
        cv[0] = c4.x; cv[1] = c4.y; cv[2] = c4.z; cv[3] = c4.w;
    } else {
        const ushort4 u = *reinterpret_cast<const ushort4*>((const unsigned short*)Cin + gidx);
        cv[0] = bf_bits2f(u.x); cv[1] = bf_bits2f(u.y);
        cv[2] = bf_bits2f(u.z); cv[3] = bf_bits2f(u.w);
    }

    float nh[4], nc[4];
#pragma unroll
    for (int k = 0; k < 4; ++k) {
        const float it = sigmoid_f(gi[k]);
        const float ot = sigmoid_f(go[k]);
        const float ft = sigmoid_f(gf[k]);
        const float ct = tanh_f(gc[k]);
        nc[k] = ft * cv[k] + it * ct;
        nh[k] = ot * tanh_f(nc[k]);
    }

    if (isF32) {
        float* oH = (float*)out;
        float* oC = oH + (size_t)BHT;
        *reinterpret_cast<float4*>(oH + gidx) = make_float4(nh[0], nh[1], nh[2], nh[3]);
        *reinterpret_cast<float4*>(oC + gidx) = make_float4(nc[0], nc[1], nc[2], nc[3]);
    } else {
        unsigned short* oH = (unsigned short*)out;
        unsigned short* oC = oH + (size_t)BHT;
        *reinterpret_cast<ushort4*>(oH + gidx) =
            make_ushort4(f2bf_bits(nh[0]), f2bf_bits(nh[1]), f2bf_bits(nh[2]), f2bf_bits(nh[3]));
        *reinterpret_cast<ushort4*>(oC + gidx) =
            make_ushort4(f2bf_bits(nc[0]), f2bf_bits(nc[1]), f2bf_bits(nc[2]), f2bf_bits(nc[3]));
    }
}

extern "C" void kernel_launch(void* const* d_in, const int* in_sizes, int n_in,
                              void* d_out, int out_size, void* d_ws, size_t ws_size,
                              hipStream_t stream) {
    (void)in_sizes; (void)n_in; (void)out_size;
    const void* X   = d_in[0];
    const void* Hm  = d_in[1];
    const void* C   = d_in[2];
    const void* Wxi = d_in[3];
    const void* Wxo = d_in[4];
    const void* Wxf = d_in[5];
    const void* Wxc = d_in[6];
    const void* bi  = d_in[7];
    const void* bo  = d_in[8];
    const void* bfp = d_in[9];
    const void* bc  = d_in[10];
    const void* Whi = d_in[11];
    const void* Who = d_in[12];
    const void* Whf = d_in[13];
    const void* Whc = d_in[14];

    __hip_bfloat16* gates = (__hip_bfloat16*)d_ws;
    const size_t flagOff = (ws_size - 4) & ~(size_t)15;   // flag at end of ws
    int* flag = (int*)((char*)d_ws + flagOff);

    // M-chunking: chunk gates buffer = rows*8192*2 bytes must fit below flag.
    int rows = B_DIM;
    while ((size_t)rows * NG * 2 > flagOff && rows > 128) rows >>= 1;

    dtype_probe_kernel<<<1, 64, 0, stream>>>((const unsigned int*)X, flag);

    const dim3 blk(256);
    for (int m0 = 0; m0 < B_DIM; m0 += rows) {
        gates_gemm_kernel<<<dim3(64, rows / 128), blk, 0, stream>>>(
            X, Hm, Wxi, Wxo, Wxf, Wxc, Whi, Who, Whf, Whc,
            bi, bo, bfp, bc, flag, m0, gates);
        lstm_pointwise_kernel<<<dim3(rows * 2048 / 1024), blk, 0, stream>>>(
            (const unsigned short*)gates, C, d_out, flag, m0);
    }
}

// Round 4
// 590.523 us; speedup vs baseline: 1.1902x; 1.1902x over previous
//
#include <hip/hip_runtime.h>
#include <hip/hip_bf16.h>
#include <cstdint>

// LSTMCell B=4096, IN=H=2048 (fp32 in/out per R3 FETCH evidence; runtime probe
// keeps bf16 safe). Pipeline: probe -> convert(fp32->bf16 into ws) ->
// m97-style bf16 GEMM w/ global_load_lds(16) -> pointwise combine.
// Fallback (ws < 160 MB): R3's ds_write GEMM with in-kernel conversion.

#define B_DIM 4096
#define K_DIM 2048            // IN == H
#define NG    8192            // 4*H
#define BHT   (B_DIM * K_DIM) // B*H elements per output tensor

// ws element-layout (bf16 elements) for the fast path:
#define CONV_X_OFF  0u                      // 8M els
#define CONV_H_OFF  (8u << 20)              // 8M els
#define CONV_W_OFF  (16u << 20)             // 8 x 4M els: Wxi,Wxo,Wxf,Wxc,Whi,Who,Whf,Whc
#define CONV_TOTAL  (48u << 20)             // 48M els = 96 MB
#define GATES_BYTE_OFF ((size_t)CONV_TOTAL * 2)          // 96 MB
#define FAST_NEED   (GATES_BYTE_OFF + (size_t)B_DIM * NG * 2 + 16)  // 160 MB + 16

using bf16x8_t  = __attribute__((ext_vector_type(8))) __bf16;
using floatx4_t = __attribute__((ext_vector_type(4))) float;
using ushort8_t = __attribute__((ext_vector_type(8))) unsigned short;

__device__ __forceinline__ float bf_bits2f(unsigned short u) {
    return __builtin_bit_cast(float, ((unsigned int)u) << 16);
}
__device__ __forceinline__ unsigned short f2bf_bits(float f) {
    return __builtin_bit_cast(unsigned short, __float2bfloat16(f));
}
__device__ __forceinline__ float sigmoid_f(float x) {
    return 1.0f / (1.0f + __expf(-x));
}
__device__ __forceinline__ float tanh_f(float x) {
    float ax = fabsf(x);
    float e  = __expf(-2.0f * ax);
    float t  = (1.0f - e) / (1.0f + e);
    return copysignf(t, x);
}

// ---------------------------------------------------------------------------
// Dtype probe: flag 0 = bf16, 1 = fp32 (R3: fp32 path ran and passed).
// ---------------------------------------------------------------------------
__global__ void dtype_probe_kernel(const unsigned int* __restrict__ X,
                                   int* __restrict__ flag) {
    const int lane = threadIdx.x;             // 64 threads, 1 block
    const unsigned int w = X[lane];
    const unsigned short hi = (unsigned short)(w >> 16);
    const unsigned short lo = (unsigned short)(w & 0xFFFFu);
    auto sane = [](unsigned short h) -> int {
        const int e = (h >> 7) & 0xFF;
        return (e >= 90 && e <= 140) || ((h & 0x7FFF) == 0);
    };
    const unsigned long long bh = __ballot(sane(hi));
    const unsigned long long bl = __ballot(sane(lo));
    if (lane == 0) {
        const int cnt = __popcll(bh) + __popcll(bl);  // bf16 ~128, fp32 ~77
        *flag = (cnt >= 112) ? 0 : 1;
    }
}

// ---------------------------------------------------------------------------
// Convert pre-pass: all 10 matrices -> contiguous bf16 in ws. 8 els/thread.
// Tensor boundaries are 4M-el aligned, blocks (2048 els) never straddle.
// ---------------------------------------------------------------------------
struct SrcPtrs { const void* p[10]; };

__global__ __launch_bounds__(256) void convert_kernel(
    SrcPtrs srcs, unsigned short* __restrict__ dst,
    const int* __restrict__ flagp)
{
    const int isF32 = *flagp;
    const unsigned int idx8 = (blockIdx.x * 256u + threadIdx.x) * 8u;
    const unsigned int r = idx8 >> 22;                 // 4M-el region id, 0..11
    int ti; unsigned int off;
    if (r < 2)      { ti = 0; off = idx8; }            // X  (8M)
    else if (r < 4) { ti = 1; off = idx8 - (8u << 20); } // H (8M)
    else            { ti = 2 + (int)(r - 4); off = idx8 - (r << 22); } // W[r-4]

    ushort8_t v;
    if (isF32) {
        const float* s = (const float*)srcs.p[ti] + off;
        const float4 f0 = *reinterpret_cast<const float4*>(s);
        const float4 f1 = *reinterpret_cast<const float4*>(s + 4);
        v = (ushort8_t){f2bf_bits(f0.x), f2bf_bits(f0.y), f2bf_bits(f0.z), f2bf_bits(f0.w),
                        f2bf_bits(f1.x), f2bf_bits(f1.y), f2bf_bits(f1.z), f2bf_bits(f1.w)};
    } else {
        v = *reinterpret_cast<const ushort8_t*>((const unsigned short*)srcs.p[ti] + off);
    }
    *reinterpret_cast<ushort8_t*>(dst + idx8) = v;
}

// ---------------------------------------------------------------------------
// Fast GEMM (m97 structure): 128x128 tile/block, 256 thr = 4 waves (2x2),
// wave 64x64 via 4x4 mfma_f32_16x16x32_bf16, BK=32, global_load_lds w=16.
// LDS K-major [row][32] bf16, unpadded (DMA layout = lane order).
// ---------------------------------------------------------------------------
__global__ __launch_bounds__(256) void gates_gemm_fast(
    const unsigned short* __restrict__ conv,  // ws bf16 region
    const void* __restrict__ bi0, const void* __restrict__ bi1,
    const void* __restrict__ bi2, const void* __restrict__ bi3,
    const int* __restrict__ flagp,
    __hip_bfloat16* __restrict__ gates)       // [4096,8192]
{
    __shared__ __align__(16) char lds[16384];

    const int tid     = threadIdx.x;
    const int bm      = blockIdx.y;           // 0..31
    const int bn      = blockIdx.x;           // 0..63, gate-major
    const int gate    = bn >> 4;
    const int nInGate = (bn & 15) << 7;

    const char* Xc = (const char*)(conv + CONV_X_OFF);
    const char* Hc = (const char*)(conv + CONV_H_OFF);
    const char* Wx = (const char*)(conv + CONV_W_OFF + (unsigned)gate * (4u << 20));
    const char* Wh = (const char*)(conv + CONV_W_OFF + (unsigned)(gate + 4) * (4u << 20));

    // staging: thread t -> row t>>2, byte (t&3)*16 within 64B row-slab.
    const int ldRow = tid >> 2;
    const int ldByte = (tid & 3) << 4;
    const size_t rowStride = (size_t)K_DIM * 2;
    const size_t rowHalf   = 64 * rowStride;
    const char* aG  = Xc + (size_t)(bm * 128 + ldRow) * rowStride + ldByte;
    const char* hG  = Hc + (size_t)(bm * 128 + ldRow) * rowStride + ldByte;
    const char* wxG = Wx + (size_t)(nInGate + ldRow) * rowStride + ldByte;
    const char* whG = Wh + (size_t)(nInGate + ldRow) * rowStride + ldByte;

    const int waveU = __builtin_amdgcn_readfirstlane(tid >> 6);
    char* const dA0 = lds + waveU * 1024;            // As rows 0..63
    char* const dA1 = lds + 4096 + waveU * 1024;     // As rows 64..127
    char* const dB0 = lds + 8192 + waveU * 1024;     // Bs rows 0..63
    char* const dB1 = lds + 12288 + waveU * 1024;    // Bs rows 64..127
    const char* const AsB = lds;
    const char* const BsB = lds + 8192;

    const int lane = tid & 63;
    const int wave = tid >> 6;
    const int wm   = (wave & 1) << 6;
    const int wn   = (wave >> 1) << 6;
    const int lr   = lane & 15;
    const int quad = lane >> 4;

    int aOff[4], bOff[4];
#pragma unroll
    for (int i = 0; i < 4; ++i) {
        aOff[i] = ((wm + i * 16 + lr) * 32 + quad * 8) * 2;
        bOff[i] = ((wn + i * 16 + lr) * 32 + quad * 8) * 2;
    }

    floatx4_t acc[4][4];
#pragma unroll
    for (int mi = 0; mi < 4; ++mi)
#pragma unroll
        for (int ni = 0; ni < 4; ++ni)
            acc[mi][ni] = (floatx4_t){0.f, 0.f, 0.f, 0.f};

#pragma unroll 1
    for (int seg = 0; seg < 2; ++seg) {
        const char* ag = seg ? hG : aG;
        const char* bg = seg ? whG : wxG;
#pragma unroll 1
        for (int kb = 0; kb < K_DIM * 2; kb += 64) {   // 64 B = 32 bf16 = BK
            __builtin_amdgcn_global_load_lds(
                (const __attribute__((address_space(1))) void*)(ag + kb),
                (__attribute__((address_space(3))) void*)dA0, 16, 0, 0);
            __builtin_amdgcn_global_load_lds(
                (const __attribute__((address_space(1))) void*)(ag + rowHalf + kb),
                (__attribute__((address_space(3))) void*)dA1, 16, 0, 0);
            __builtin_amdgcn_global_load_lds(
                (const __attribute__((address_space(1))) void*)(bg + kb),
                (__attribute__((address_space(3))) void*)dB0, 16, 0, 0);
            __builtin_amdgcn_global_load_lds(
                (const __attribute__((address_space(1))) void*)(bg + rowHalf + kb),
                (__attribute__((address_space(3))) void*)dB1, 16, 0, 0);
            __syncthreads();

            bf16x8_t af[4], bw[4];
#pragma unroll
            for (int i = 0; i < 4; ++i) af[i] = *reinterpret_cast<const bf16x8_t*>(AsB + aOff[i]);
#pragma unroll
            for (int i = 0; i < 4; ++i) bw[i] = *reinterpret_cast<const bf16x8_t*>(BsB + bOff[i]);
#pragma unroll
            for (int mi = 0; mi < 4; ++mi)
#pragma unroll
                for (int ni = 0; ni < 4; ++ni)
                    acc[mi][ni] = __builtin_amdgcn_mfma_f32_16x16x32_bf16(
                        af[mi], bw[ni], acc[mi][ni], 0, 0, 0);
            __syncthreads();
        }
    }

    const void* bs = (gate == 0) ? bi0 : (gate == 1) ? bi1 : (gate == 2) ? bi2 : bi3;
    const int isF32 = *flagp;
    float bv[4];
#pragma unroll
    for (int ni = 0; ni < 4; ++ni) {
        const int col = nInGate + wn + ni * 16 + lr;
        bv[ni] = isF32 ? ((const float*)bs)[col]
                       : __bfloat162float(((const __hip_bfloat16*)bs)[col]);
    }

    // C/D layout: col=lane&15, row=quad*4+reg (m89-verified).
#pragma unroll
    for (int mi = 0; mi < 4; ++mi) {
        const int rowBase = bm * 128 + wm + mi * 16 + quad * 4;
#pragma unroll
        for (int ni = 0; ni < 4; ++ni) {
            const size_t colBase = (size_t)gate * 2048 + nInGate + wn + ni * 16 + lr;
#pragma unroll
            for (int r = 0; r < 4; ++r)
                gates[(size_t)(rowBase + r) * NG + colBase] =
                    __float2bfloat16(acc[mi][ni][r] + bv[ni]);
        }
    }
}

// ---------------------------------------------------------------------------
// Slow fallback GEMM (R3, passed): ds_write staging + in-kernel conversion.
// ---------------------------------------------------------------------------
__global__ __launch_bounds__(256) void gates_gemm_slow(
    const void* __restrict__ X, const void* __restrict__ Hm,
    const void* __restrict__ Wx0, const void* __restrict__ Wx1,
    const void* __restrict__ Wx2, const void* __restrict__ Wx3,
    const void* __restrict__ Wh0, const void* __restrict__ Wh1,
    const void* __restrict__ Wh2, const void* __restrict__ Wh3,
    const void* __restrict__ bi0, const void* __restrict__ bi1,
    const void* __restrict__ bi2, const void* __restrict__ bi3,
    const int* __restrict__ flagp, int m0,
    __hip_bfloat16* __restrict__ gates)
{
    __shared__ __align__(16) char lds[16384];
    const int isF32 = *flagp;
    const int esz   = isF32 ? 4 : 2;

    const int tid     = threadIdx.x;
    const int bm      = blockIdx.y;
    const int bn      = blockIdx.x;
    const int gate    = bn >> 4;
    const int nInGate = (bn & 15) << 7;

    const void* Wx = (gate == 0) ? Wx0 : (gate == 1) ? Wx1 : (gate == 2) ? Wx2 : Wx3;
    const void* Wh = (gate == 0) ? Wh0 : (gate == 1) ? Wh1 : (gate == 2) ? Wh2 : Wh3;
    const void* bs = (gate == 0) ? bi0 : (gate == 1) ? bi1 : (gate == 2) ? bi2 : bi3;

    const int ldRow = tid >> 2;
    const int sub   = tid & 3;
    const size_t rowStride = (size_t)K_DIM * esz;
    const size_t rowHalf   = 64 * rowStride;
    const char* aG  = (const char*)X  + (size_t)(m0 + bm * 128 + ldRow) * rowStride + (size_t)sub * 8 * esz;
    const char* hG  = (const char*)Hm + (size_t)(m0 + bm * 128 + ldRow) * rowStride + (size_t)sub * 8 * esz;
    const char* wxG = (const char*)Wx + (size_t)(nInGate + ldRow) * rowStride + (size_t)sub * 8 * esz;
    const char* whG = (const char*)Wh + (size_t)(nInGate + ldRow) * rowStride + (size_t)sub * 8 * esz;

    char* const dA0 = lds + tid * 16;
    char* const dA1 = lds + 4096 + tid * 16;
    char* const dB0 = lds + 8192 + tid * 16;
    char* const dB1 = lds + 12288 + tid * 16;
    const char* const AsB = lds;
    const char* const BsB = lds + 8192;

    const int lane = tid & 63;
    const int wave = tid >> 6;
    const int wm   = (wave & 1) << 6;
    const int wn   = (wave >> 1) << 6;
    const int lr   = lane & 15;
    const int quad = lane >> 4;

    int aOff[4], bOff[4];
#pragma unroll
    for (int i = 0; i < 4; ++i) {
        aOff[i] = ((wm + i * 16 + lr) * 32 + quad * 8) * 2;
        bOff[i] = ((wn + i * 16 + lr) * 32 + quad * 8) * 2;
    }

    floatx4_t acc[4][4];
#pragma unroll
    for (int mi = 0; mi < 4; ++mi)
#pragma unroll
        for (int ni = 0; ni < 4; ++ni)
            acc[mi][ni] = (floatx4_t){0.f, 0.f, 0.f, 0.f};

#pragma unroll 1
    for (int seg = 0; seg < 2; ++seg) {
        const char* ag = seg ? hG : aG;
        const char* bg = seg ? whG : wxG;
#pragma unroll 1
        for (int ke = 0; ke < K_DIM; ke += 32) {
            const size_t kb = (size_t)ke * esz;
            ushort8_t va0, va1, vb0, vb1;
            if (!isF32) {
                va0 = *reinterpret_cast<const ushort8_t*>(ag + kb);
                va1 = *reinterpret_cast<const ushort8_t*>(ag + rowHalf + kb);
                vb0 = *reinterpret_cast<const ushort8_t*>(bg + kb);
                vb1 = *reinterpret_cast<const ushort8_t*>(bg + rowHalf + kb);
            } else {
                const char* p; float4 f0, f1;
                p = ag + kb;           f0 = *reinterpret_cast<const float4*>(p);
                f1 = *reinterpret_cast<const float4*>(p + 16);
                va0 = (ushort8_t){f2bf_bits(f0.x), f2bf_bits(f0.y), f2bf_bits(f0.z), f2bf_bits(f0.w),
                                  f2bf_bits(f1.x), f2bf_bits(f1.y), f2bf_bits(f1.z), f2bf_bits(f1.w)};
                p = ag + rowHalf + kb; f0 = *reinterpret_cast<const float4*>(p);
                f1 = *reinterpret_cast<const float4*>(p + 16);
                va1 = (ushort8_t){f2bf_bits(f0.x), f2bf_bits(f0.y), f2bf_bits(f0.z), f2bf_bits(f0.w),
                                  f2bf_bits(f1.x), f2bf_bits(f1.y), f2bf_bits(f1.z), f2bf_bits(f1.w)};
                p = bg + kb;           f0 = *reinterpret_cast<const float4*>(p);
                f1 = *reinterpret_cast<const float4*>(p + 16);
                vb0 = (ushort8_t){f2bf_bits(f0.x), f2bf_bits(f0.y), f2bf_bits(f0.z), f2bf_bits(f0.w),
                                  f2bf_bits(f1.x), f2bf_bits(f1.y), f2bf_bits(f1.z), f2bf_bits(f1.w)};
                p = bg + rowHalf + kb; f0 = *reinterpret_cast<const float4*>(p);
                f1 = *reinterpret_cast<const float4*>(p + 16);
                vb1 = (ushort8_t){f2bf_bits(f0.x), f2bf_bits(f0.y), f2bf_bits(f0.z), f2bf_bits(f0.w),
                                  f2bf_bits(f1.x), f2bf_bits(f1.y), f2bf_bits(f1.z), f2bf_bits(f1.w)};
            }
            __syncthreads();
            *reinterpret_cast<ushort8_t*>(dA0) = va0;
            *reinterpret_cast<ushort8_t*>(dA1) = va1;
            *reinterpret_cast<ushort8_t*>(dB0) = vb0;
            *reinterpret_cast<ushort8_t*>(dB1) = vb1;
            __syncthreads();

            bf16x8_t af[4], bw[4];
#pragma unroll
            for (int i = 0; i < 4; ++i) af[i] = *reinterpret_cast<const bf16x8_t*>(AsB + aOff[i]);
#pragma unroll
            for (int i = 0; i < 4; ++i) bw[i] = *reinterpret_cast<const bf16x8_t*>(BsB + bOff[i]);
#pragma unroll
            for (int mi = 0; mi < 4; ++mi)
#pragma unroll
                for (int ni = 0; ni < 4; ++ni)
                    acc[mi][ni] = __builtin_amdgcn_mfma_f32_16x16x32_bf16(
                        af[mi], bw[ni], acc[mi][ni], 0, 0, 0);
        }
    }

    float bv[4];
#pragma unroll
    for (int ni = 0; ni < 4; ++ni) {
        const int col = nInGate + wn + ni * 16 + lr;
        bv[ni] = isF32 ? ((const float*)bs)[col]
                       : __bfloat162float(((const __hip_bfloat16*)bs)[col]);
    }
#pragma unroll
    for (int mi = 0; mi < 4; ++mi) {
        const int rowBase = bm * 128 + wm + mi * 16 + quad * 4;
#pragma unroll
        for (int ni = 0; ni < 4; ++ni) {
            const size_t colBase = (size_t)gate * 2048 + nInGate + wn + ni * 16 + lr;
#pragma unroll
            for (int r = 0; r < 4; ++r)
                gates[(size_t)(rowBase + r) * NG + colBase] =
                    __float2bfloat16(acc[mi][ni][r] + bv[ni]);
        }
    }
}

// ---------------------------------------------------------------------------
// Pointwise LSTM combine (chunk-aware; m0=0, full grid in fast path).
// ---------------------------------------------------------------------------
__global__ __launch_bounds__(256) void lstm_pointwise_kernel(
    const unsigned short* __restrict__ gates,
    const void* __restrict__ Cin,
    void* __restrict__ out,
    const int* __restrict__ flagp, int m0)
{
    const int isF32 = *flagp;
    const int lidx = (blockIdx.x * 256 + threadIdx.x) * 4;
    const int b = lidx >> 11;
    const int j = lidx & 2047;
    const unsigned short* g = gates + (size_t)b * NG + j;
    const size_t gidx = (size_t)m0 * 2048 + (size_t)lidx;

    const ushort4 ui = *reinterpret_cast<const ushort4*>(g);
    const ushort4 uo = *reinterpret_cast<const ushort4*>(g + 2048);
    const ushort4 uf = *reinterpret_cast<const ushort4*>(g + 4096);
    const ushort4 uc = *reinterpret_cast<const ushort4*>(g + 6144);
    const float gi[4] = {bf_bits2f(ui.x), bf_bits2f(ui.y), bf_bits2f(ui.z), bf_bits2f(ui.w)};
    const float go[4] = {bf_bits2f(uo.x), bf_bits2f(uo.y), bf_bits2f(uo.z), bf_bits2f(uo.w)};
    const float gf[4] = {bf_bits2f(uf.x), bf_bits2f(uf.y), bf_bits2f(uf.z), bf_bits2f(uf.w)};
    const float gc[4] = {bf_bits2f(uc.x), bf_bits2f(uc.y), bf_bits2f(uc.z), bf_bits2f(uc.w)};

    float cv[4];
    if (isF32) {
        const float4 c4 = *reinterpret_cast<const float4*>((const float*)Cin + gidx);
        cv[0] = c4.x; cv[1] = c4.y; cv[2] = c4.z; cv[3] = c4.w;
    } else {
        const ushort4 u = *reinterpret_cast<const ushort4*>((const unsigned short*)Cin + gidx);
        cv[0] = bf_bits2f(u.x); cv[1] = bf_bits2f(u.y);
        cv[2] = bf_bits2f(u.z); cv[3] = bf_bits2f(u.w);
    }

    float nh[4], nc[4];
#pragma unroll
    for (int k = 0; k < 4; ++k) {
        const float it = sigmoid_f(gi[k]);
        const float ot = sigmoid_f(go[k]);
        const float ft = sigmoid_f(gf[k]);
        const float ct = tanh_f(gc[k]);
        nc[k] = ft * cv[k] + it * ct;
        nh[k] = ot * tanh_f(nc[k]);
    }

    if (isF32) {
        float* oH = (float*)out;
        float* oC = oH + (size_t)BHT;
        *reinterpret_cast<float4*>(oH + gidx) = make_float4(nh[0], nh[1], nh[2], nh[3]);
        *reinterpret_cast<float4*>(oC + gidx) = make_float4(nc[0], nc[1], nc[2], nc[3]);
    } else {
        unsigned short* oH = (unsigned short*)out;
        unsigned short* oC = oH + (size_t)BHT;
        *reinterpret_cast<ushort4*>(oH + gidx) =
            make_ushort4(f2bf_bits(nh[0]), f2bf_bits(nh[1]), f2bf_bits(nh[2]), f2bf_bits(nh[3]));
        *reinterpret_cast<ushort4*>(oC + gidx) =
            make_ushort4(f2bf_bits(nc[0]), f2bf_bits(nc[1]), f2bf_bits(nc[2]), f2bf_bits(nc[3]));
    }
}

extern "C" void kernel_launch(void* const* d_in, const int* in_sizes, int n_in,
                              void* d_out, int out_size, void* d_ws, size_t ws_size,
                              hipStream_t stream) {
    (void)in_sizes; (void)n_in; (void)out_size;
    const void* X   = d_in[0];
    const void* Hm  = d_in[1];
    const void* C   = d_in[2];
    const void* Wxi = d_in[3];
    const void* Wxo = d_in[4];
    const void* Wxf = d_in[5];
    const void* Wxc = d_in[6];
    const void* bi  = d_in[7];
    const void* bo  = d_in[8];
    const void* bfp = d_in[9];
    const void* bc  = d_in[10];
    const void* Whi = d_in[11];
    const void* Who = d_in[12];
    const void* Whf = d_in[13];
    const void* Whc = d_in[14];

    const size_t flagOff = (ws_size - 4) & ~(size_t)15;
    int* flag = (int*)((char*)d_ws + flagOff);
    const dim3 blk(256);

    dtype_probe_kernel<<<1, 64, 0, stream>>>((const unsigned int*)X, flag);

    if (ws_size >= FAST_NEED) {
        unsigned short* conv  = (unsigned short*)d_ws;
        __hip_bfloat16* gates = (__hip_bfloat16*)((char*)d_ws + GATES_BYTE_OFF);

        SrcPtrs sp;
        sp.p[0] = X;  sp.p[1] = Hm;
        sp.p[2] = Wxi; sp.p[3] = Wxo; sp.p[4] = Wxf; sp.p[5] = Wxc;
        sp.p[6] = Whi; sp.p[7] = Who; sp.p[8] = Whf; sp.p[9] = Whc;
        convert_kernel<<<dim3(CONV_TOTAL / 2048), blk, 0, stream>>>(sp, conv, flag);

        gates_gemm_fast<<<dim3(64, 32), blk, 0, stream>>>(
            conv, bi, bo, bfp, bc, flag, gates);
        lstm_pointwise_kernel<<<dim3(BHT / 1024), blk, 0, stream>>>(
            (const unsigned short*)gates, C, d_out, flag, 0);
    } else {
        __hip_bfloat16* gates = (__hip_bfloat16*)d_ws;
        int rows = B_DIM;
        while ((size_t)rows * NG * 2 > flagOff && rows > 128) rows >>= 1;
        for (int m0 = 0; m0 < B_DIM; m0 += rows) {
            gates_gemm_slow<<<dim3(64, rows / 128), blk, 0, stream>>>(
                X, Hm, Wxi, Wxo, Wxf, Wxc, Whi, Who, Whf, Whc,
                bi, bo, bfp, bc, flag, m0, gates);
            lstm_pointwise_kernel<<<dim3(rows * 2048 / 1024), blk, 0, stream>>>(
                (const unsigned short*)gates, C, d_out, flag, m0);
        }
    }
}